// Round 9
// baseline (80.844 us; speedup 1.0000x reference)
//
#include <hip/hip_runtime.h>
#include <math.h>

// Quanvolution closed form (Heisenberg picture) — R9 = R7's kernel (best:
// 14.54us) + a TIMING DIAGNOSTIC: the identical kernel dispatched 8x in one
// graph (1x -> d_out correct output, 7x -> d_ws sink). Host dur_us ~ OH + 8T
// vs R7's OH + T separates per-replay overhead OH from true GPU time T.
//   T = (dur_us - 14.54)/7 ; OH = 14.54 - T.
// Next round reverts to the single-dispatch kernel and acts on T vs OH.

#define N_PAIRS    (8192 * 98)     // pairs of adjacent 2x2 patches
#define HALF_PAIRS (N_PAIRS / 2)   // 401408 threads; 1568 blocks of 256
#define IMG_HALF_OFF (4096 * 784)  // float offset between pair t and t+HALF

typedef float v2f __attribute__((ext_vector_type(2)));

static __device__ __forceinline__ v2f splat(float v) { v2f r; r.x = v; r.y = v; return r; }
static __device__ __forceinline__ v2f vfma(v2f a, v2f b, v2f c) {
    return __builtin_elementwise_fma(a, b, c);
}
static __device__ __forceinline__ float uni(float v) {
    return __int_as_float(__builtin_amdgcn_readfirstlane(__float_as_int(v)));
}

// cos(x), sin(x) for x in [0,1): Taylor, err < 3e-5.
static __device__ __forceinline__ void trig01(v2f x, v2f& c, v2f& s) {
    v2f u = x * x;
    v2f sp = vfma(u, vfma(u, vfma(u, splat(-1.9841270e-4f), splat(8.3333338e-3f)),
                          splat(-1.6666667e-1f)), splat(1.0f));
    s = x * sp;
    c = vfma(u, vfma(u, vfma(u, vfma(u, splat(2.4801588e-5f), splat(-1.3888889e-3f)),
                             splat(4.1666668e-2f)), splat(-0.5f)), splat(1.0f));
}

static __device__ __forceinline__ void eval_pair(
    float4 row0, float4 row1,
    const float* __restrict__ cp, const float* __restrict__ sp,
    const float* __restrict__ K,
    float4& o0, float4& o1)
{
    v2f x0; x0.x = row0.x; x0.y = row0.z;
    v2f x1; x1.x = row0.y; x1.y = row0.w;
    v2f x2; x2.x = row1.x; x2.y = row1.z;
    v2f x3; x3.x = row1.y; x3.y = row1.w;

    v2f C0, S0, C1, S1, C2, S2, C3, S3, cx, sx;
    trig01(x0, cx, sx);
    C0 = cx * splat(cp[0]) - sx * splat(sp[0]); S0 = sx * splat(cp[0]) + cx * splat(sp[0]);
    trig01(x1, cx, sx);
    C1 = cx * splat(cp[1]) - sx * splat(sp[1]); S1 = sx * splat(cp[1]) + cx * splat(sp[1]);
    trig01(x2, cx, sx);
    C2 = cx * splat(cp[2]) - sx * splat(sp[2]); S2 = sx * splat(cp[2]) + cx * splat(sp[2]);
    trig01(x3, cx, sx);
    C3 = cx * splat(cp[3]) - sx * splat(sp[3]); S3 = sx * splat(cp[3]) + cx * splat(sp[3]);

    v2f C0C1 = C0 * C1, C0C2 = C0 * C2, C0C3 = C0 * C3;
    v2f C1C3 = C1 * C3, C2C3 = C2 * C3;
    v2f S0S1 = S0 * S1, S0S2 = S0 * S2, S0S3 = S0 * S3;
    v2f S1S2 = S1 * S2, S1S3 = S1 * S3, S2S3 = S2 * S3;
    v2f C2S3 = C2 * S3;

    v2f z0 =            splat(K[0])  * (C0 * C1C3);
    z0 = vfma(splat(K[1]),  S0S1 * C2S3, z0);
    z0 = vfma(splat(K[2]),  S1S2 * C3,   z0);
    z0 = vfma(splat(K[3]),  S0,          z0);

    v2f z1 =            splat(K[4])  * (C0 * C2C3);
    z1 = vfma(splat(K[5]),  S0S2, z1);

    v2f z2 =            splat(K[6])  * C1C3;
    z2 = vfma(splat(K[7]),  C0C3 * S1S2, z2);
    z2 = vfma(splat(K[8]),  S0S1 * C2,   z2);
    z2 = vfma(splat(K[9]),  S0S3,        z2);

    v2f z3 =            splat(K[10]) * C0C2;
    z3 = vfma(splat(K[11]), C1 * S2S3,        z3);
    z3 = vfma(splat(K[12]), C0 * S1S3,        z3);
    z3 = vfma(splat(K[13]), S0 * (C1 * C2C3), z3);
    z3 = vfma(splat(K[14]), C2S3,             z3);
    z3 = vfma(splat(K[15]), C0C1 * S2,        z3);
    z3 = vfma(splat(K[16]), S0S2 * C3,        z3);
    z3 = vfma(splat(K[17]), S1,               z3);

    o0 = make_float4(z0.x, z1.x, z2.x, z3.x);
    o1 = make_float4(z0.y, z1.y, z2.y, z3.y);
}

__global__ __launch_bounds__(256) void quanv_kernel(
    const float* __restrict__ x,       // (8192, 28, 28)
    const float* __restrict__ params,  // (2, 4)
    float* __restrict__ out)           // (8192, 784) or scratch sink
{
    int t = blockIdx.x * blockDim.x + threadIdx.x;   // [0, HALF_PAIRS)

    int b    = t / 98;
    int q    = t - b * 98;
    int r    = q / 7;
    int pcol = q - r * 7;

    const float* pxA = x + b * 784 + (2 * r) * 28 + 4 * pcol;
    const float* pxB = pxA + IMG_HALF_OFF;
    float4 r0A = *reinterpret_cast<const float4*>(pxA);
    float4 r1A = *reinterpret_cast<const float4*>(pxA + 28);
    float4 r0B = *reinterpret_cast<const float4*>(pxB);
    float4 r1B = *reinterpret_cast<const float4*>(pxB + 28);

    float cp[4], sp[4], cl[4], sl[4];
#pragma unroll
    for (int w = 0; w < 4; ++w) {
        float s_, c_;
        __sincosf(params[w], &s_, &c_);
        cp[w] = uni(c_); sp[w] = uni(s_);
        __sincosf(params[4 + w], &s_, &c_);
        cl[w] = uni(c_); sl[w] = uni(s_);
    }
    float K[18];
    K[0]  = uni( cl[1]*cl[2]*cl[3]);
    K[1]  = uni(-cl[1]*cl[2]*sl[3]);
    K[2]  = uni(-sl[1]*cl[2]*cl[3]);
    K[3]  = uni(-sl[1]*sl[2]*sl[3]);
    K[4]  = uni( cl[0]*cl[1]);
    K[5]  = uni( sl[0]*sl[1]);
    K[6]  = uni( cl[0]*cl[1]*cl[2]);
    K[7]  = uni(-cl[0]*sl[1]*cl[2]);
    K[8]  = uni(-sl[0]*cl[1]*cl[2]);
    K[9]  = uni(-sl[0]*sl[1]*sl[2]);
    K[10] = uni( cl[0]*cl[1]*cl[2]*cl[3]);
    K[11] = uni(-cl[0]*cl[1]*sl[2]*cl[3]);
    K[12] = uni( cl[0]*sl[1]*sl[2]*cl[3]);
    K[13] = uni(-cl[0]*sl[1]*sl[2]*sl[3]);
    K[14] = uni( sl[0]*cl[1]*cl[2]*sl[3]);
    K[15] = uni(-sl[0]*cl[1]*sl[2]*sl[3]);
    K[16] = uni( sl[0]*sl[1]*cl[2]*cl[3]);
    K[17] = uni( sl[0]*sl[1]*sl[2]*sl[3]);

    float4 o0, o1;
    eval_pair(r0A, r1A, cp, sp, K, o0, o1);
    {
        float4* o = reinterpret_cast<float4*>(out + (size_t)t * 8);
        o[0] = o0; o[1] = o1;
    }
    eval_pair(r0B, r1B, cp, sp, K, o0, o1);
    {
        float4* o = reinterpret_cast<float4*>(out + ((size_t)t + HALF_PAIRS) * 8);
        o[0] = o0; o[1] = o1;
    }
}

extern "C" void kernel_launch(void* const* d_in, const int* in_sizes, int n_in,
                              void* d_out, int out_size, void* d_ws, size_t ws_size,
                              hipStream_t stream) {
    const float* x      = (const float*)d_in[0];  // (8192,28,28) f32
    const float* params = (const float*)d_in[1];  // (2,4) f32
    float* out          = (float*)d_out;          // (8192,784) f32
    float* sink         = (float*)d_ws;           // >=25.7MB scratch sink

    const int block = 256;
    const int grid  = HALF_PAIRS / block;         // 1568, exact

    // Dispatch 1: correct output.
    quanv_kernel<<<grid, block, 0, stream>>>(x, params, out);

    // Dispatches 2..8: identical work into scratch (timing diagnostic only).
#pragma unroll
    for (int i = 0; i < 7; ++i)
        quanv_kernel<<<grid, block, 0, stream>>>(x, params, sink);
}

// Round 10
// 14.501 us; speedup vs baseline: 5.5751x; 5.5751x over previous
//
#include <hip/hip_runtime.h>
#include <math.h>

// Quanvolution closed form (Heisenberg picture) — FINAL (restores R7's best).
// For each 2x2 patch with pixels x0..x3, params p0 (layer0), p1 (layer1):
//   theta_w = x_w + p0_w ; C_w = cos(theta_w), S_w = sin(theta_w)
//   c_w = cos(p1_w), s_w = sin(p1_w)
//   z0 = A C0C1C3 + B S0S1C2S3 + D S1S2C3 + E S0
//   z1 = F C0C2C3 + G S0S2
//   z2 = H C1C3 + I C0S1S2C3 + J S0S1C2 + K S0S3
//   z3 = L C0C2 + M C1S2S3 + N C0S1S3 + O S0C1C2C3 + P C2S3 + Q C0C1S2
//        + R S0S2C3 + T S1
// (18 Pauli-string monomials; entire 16-amplitude evolution eliminated.)
//
// Structure: single dispatch; 2 patch-pairs per thread (images b, b+4096)
// with all 4 float4 loads hoisted for MLP; packed <2 x float> math
// (v_pk_fma_f32); wave-uniform param trig readfirstlane'd into SGPRs.
//
// Measured (R9 8x-dispatch separation): true GPU time T ~= 9.5us vs memory
// floor 6.1-8.2us (25.7MB write + ~26MB read, partly L3-absorbed); fixed
// per-replay overhead ~= 5.1us. Host-visible 14.5us is therefore ~memory-
// bound + invariant overhead; remaining in-dispatch headroom <~1.3us.

#define N_PAIRS    (8192 * 98)     // pairs of adjacent 2x2 patches
#define HALF_PAIRS (N_PAIRS / 2)   // 401408 threads; 1568 blocks of 256
#define IMG_HALF_OFF (4096 * 784)  // float offset between pair t and t+HALF

typedef float v2f __attribute__((ext_vector_type(2)));

static __device__ __forceinline__ v2f splat(float v) { v2f r; r.x = v; r.y = v; return r; }
static __device__ __forceinline__ v2f vfma(v2f a, v2f b, v2f c) {
    return __builtin_elementwise_fma(a, b, c);
}
static __device__ __forceinline__ float uni(float v) {
    return __int_as_float(__builtin_amdgcn_readfirstlane(__float_as_int(v)));
}

// cos(x), sin(x) for x in [0,1): Taylor, err < 3e-5.
static __device__ __forceinline__ void trig01(v2f x, v2f& c, v2f& s) {
    v2f u = x * x;
    v2f sp = vfma(u, vfma(u, vfma(u, splat(-1.9841270e-4f), splat(8.3333338e-3f)),
                          splat(-1.6666667e-1f)), splat(1.0f));
    s = x * sp;
    c = vfma(u, vfma(u, vfma(u, vfma(u, splat(2.4801588e-5f), splat(-1.3888889e-3f)),
                             splat(4.1666668e-2f)), splat(-0.5f)), splat(1.0f));
}

static __device__ __forceinline__ void eval_pair(
    float4 row0, float4 row1,
    const float* __restrict__ cp, const float* __restrict__ sp,
    const float* __restrict__ K,
    float4& o0, float4& o1)
{
    v2f x0; x0.x = row0.x; x0.y = row0.z;
    v2f x1; x1.x = row0.y; x1.y = row0.w;
    v2f x2; x2.x = row1.x; x2.y = row1.z;
    v2f x3; x3.x = row1.y; x3.y = row1.w;

    v2f C0, S0, C1, S1, C2, S2, C3, S3, cx, sx;
    trig01(x0, cx, sx);
    C0 = cx * splat(cp[0]) - sx * splat(sp[0]); S0 = sx * splat(cp[0]) + cx * splat(sp[0]);
    trig01(x1, cx, sx);
    C1 = cx * splat(cp[1]) - sx * splat(sp[1]); S1 = sx * splat(cp[1]) + cx * splat(sp[1]);
    trig01(x2, cx, sx);
    C2 = cx * splat(cp[2]) - sx * splat(sp[2]); S2 = sx * splat(cp[2]) + cx * splat(sp[2]);
    trig01(x3, cx, sx);
    C3 = cx * splat(cp[3]) - sx * splat(sp[3]); S3 = sx * splat(cp[3]) + cx * splat(sp[3]);

    v2f C0C1 = C0 * C1, C0C2 = C0 * C2, C0C3 = C0 * C3;
    v2f C1C3 = C1 * C3, C2C3 = C2 * C3;
    v2f S0S1 = S0 * S1, S0S2 = S0 * S2, S0S3 = S0 * S3;
    v2f S1S2 = S1 * S2, S1S3 = S1 * S3, S2S3 = S2 * S3;
    v2f C2S3 = C2 * S3;

    v2f z0 =            splat(K[0])  * (C0 * C1C3);
    z0 = vfma(splat(K[1]),  S0S1 * C2S3, z0);
    z0 = vfma(splat(K[2]),  S1S2 * C3,   z0);
    z0 = vfma(splat(K[3]),  S0,          z0);

    v2f z1 =            splat(K[4])  * (C0 * C2C3);
    z1 = vfma(splat(K[5]),  S0S2, z1);

    v2f z2 =            splat(K[6])  * C1C3;
    z2 = vfma(splat(K[7]),  C0C3 * S1S2, z2);
    z2 = vfma(splat(K[8]),  S0S1 * C2,   z2);
    z2 = vfma(splat(K[9]),  S0S3,        z2);

    v2f z3 =            splat(K[10]) * C0C2;
    z3 = vfma(splat(K[11]), C1 * S2S3,        z3);
    z3 = vfma(splat(K[12]), C0 * S1S3,        z3);
    z3 = vfma(splat(K[13]), S0 * (C1 * C2C3), z3);
    z3 = vfma(splat(K[14]), C2S3,             z3);
    z3 = vfma(splat(K[15]), C0C1 * S2,        z3);
    z3 = vfma(splat(K[16]), S0S2 * C3,        z3);
    z3 = vfma(splat(K[17]), S1,               z3);

    o0 = make_float4(z0.x, z1.x, z2.x, z3.x);
    o1 = make_float4(z0.y, z1.y, z2.y, z3.y);
}

__global__ __launch_bounds__(256) void quanv_kernel(
    const float* __restrict__ x,       // (8192, 28, 28)
    const float* __restrict__ params,  // (2, 4)
    float* __restrict__ out)           // (8192, 784)
{
    int t = blockIdx.x * blockDim.x + threadIdx.x;   // [0, HALF_PAIRS)

    int b    = t / 98;
    int q    = t - b * 98;
    int r    = q / 7;
    int pcol = q - r * 7;

    const float* pxA = x + b * 784 + (2 * r) * 28 + 4 * pcol;
    const float* pxB = pxA + IMG_HALF_OFF;
    float4 r0A = *reinterpret_cast<const float4*>(pxA);
    float4 r1A = *reinterpret_cast<const float4*>(pxA + 28);
    float4 r0B = *reinterpret_cast<const float4*>(pxB);
    float4 r1B = *reinterpret_cast<const float4*>(pxB + 28);

    float cp[4], sp[4], cl[4], sl[4];
#pragma unroll
    for (int w = 0; w < 4; ++w) {
        float s_, c_;
        __sincosf(params[w], &s_, &c_);
        cp[w] = uni(c_); sp[w] = uni(s_);
        __sincosf(params[4 + w], &s_, &c_);
        cl[w] = uni(c_); sl[w] = uni(s_);
    }
    float K[18];
    K[0]  = uni( cl[1]*cl[2]*cl[3]);        // A
    K[1]  = uni(-cl[1]*cl[2]*sl[3]);        // B
    K[2]  = uni(-sl[1]*cl[2]*cl[3]);        // D
    K[3]  = uni(-sl[1]*sl[2]*sl[3]);        // E
    K[4]  = uni( cl[0]*cl[1]);              // F
    K[5]  = uni( sl[0]*sl[1]);              // G
    K[6]  = uni( cl[0]*cl[1]*cl[2]);        // H
    K[7]  = uni(-cl[0]*sl[1]*cl[2]);        // I
    K[8]  = uni(-sl[0]*cl[1]*cl[2]);        // J
    K[9]  = uni(-sl[0]*sl[1]*sl[2]);        // K
    K[10] = uni( cl[0]*cl[1]*cl[2]*cl[3]);  // L
    K[11] = uni(-cl[0]*cl[1]*sl[2]*cl[3]);  // M
    K[12] = uni( cl[0]*sl[1]*sl[2]*cl[3]);  // N
    K[13] = uni(-cl[0]*sl[1]*sl[2]*sl[3]);  // O
    K[14] = uni( sl[0]*cl[1]*cl[2]*sl[3]);  // P
    K[15] = uni(-sl[0]*cl[1]*sl[2]*sl[3]);  // Q
    K[16] = uni( sl[0]*sl[1]*cl[2]*cl[3]);  // R
    K[17] = uni( sl[0]*sl[1]*sl[2]*sl[3]);  // T

    float4 o0, o1;
    eval_pair(r0A, r1A, cp, sp, K, o0, o1);
    {
        float4* o = reinterpret_cast<float4*>(out + (size_t)t * 8);
        o[0] = o0; o[1] = o1;
    }
    eval_pair(r0B, r1B, cp, sp, K, o0, o1);
    {
        float4* o = reinterpret_cast<float4*>(out + ((size_t)t + HALF_PAIRS) * 8);
        o[0] = o0; o[1] = o1;
    }
}

extern "C" void kernel_launch(void* const* d_in, const int* in_sizes, int n_in,
                              void* d_out, int out_size, void* d_ws, size_t ws_size,
                              hipStream_t stream) {
    const float* x      = (const float*)d_in[0];  // (8192,28,28) f32
    const float* params = (const float*)d_in[1];  // (2,4) f32
    float* out          = (float*)d_out;          // (8192,784) f32

    const int block = 256;
    const int grid  = HALF_PAIRS / block;         // 1568, exact
    quanv_kernel<<<grid, block, 0, stream>>>(x, params, out);
}